// Round 1
// baseline (210.865 us; speedup 1.0000x reference)
//
#include <hip/hip_runtime.h>
#include <math.h>

#define NTGT 512
#define NA 3
#define NCLS 80

__device__ __constant__ float c_anch[3][3][2] = {
  {{10.f,13.f},{16.f,30.f},{33.f,23.f}},
  {{30.f,61.f},{62.f,45.f},{59.f,119.f}},
  {{116.f,90.f},{156.f,198.f},{373.f,326.f}},
};

__device__ inline float sigm(float x){ return 1.0f/(1.0f+expf(-x)); }
__device__ inline float bcel(float x, float z){
  return fmaxf(x,0.0f) - x*z + log1pf(expf(-fabsf(x)));
}
__device__ inline double wred(double v){
  #pragma unroll
  for(int o=32;o;o>>=1) v += __shfl_down(v,o);
  return v;
}

// One thread per (offset c, anchor a, target n) entry for one level.
// acc layout (doubles): per level l: [l*4+0]=box_sum, [l*4+1]=cls_sum,
// [l*4+2]=valid count, [l*4+3]=obj correction sum (-x*giou_t).
// acc[12] = weighted softplus total (filled by k_obj).
template<int LVL, int H, int W>
__global__ __launch_bounds__(256)
void k_entries(const float* __restrict__ p, const float* __restrict__ tg,
               double* __restrict__ acc)
{
  const int e = blockIdx.x*256 + threadIdx.x;      // e < 5*3*512 = 7680 exactly
  const int c = e / (NA*NTGT);
  const int a = (e / NTGT) % NA;
  const int n = e % NTGT;

  const float t0 = tg[n*6+0];                      // image idx
  const float t1 = tg[n*6+1];                      // class idx
  const float tx = tg[n*6+2]*(float)W;
  const float ty = tg[n*6+3]*(float)H;
  const float tw = tg[n*6+4]*(float)W;
  const float th = tg[n*6+5]*(float)H;

  const float aw = c_anch[LVL][a][0], ah = c_anch[LVL][a][1];
  const float rw = tw/aw, rh = th/ah;
  const float mr = fmaxf(fmaxf(rw, 1.0f/rw), fmaxf(rh, 1.0f/rh));
  const bool sel = mr < 4.0f;

  const float fx = tx - floorf(tx);
  const float fy = ty - floorf(ty);
  float ox = 0.f, oy = 0.f; bool cond = true;
  if (c==1){ cond = (fx<0.5f) && (tx>1.0f);              ox =  0.5f; }
  else if (c==2){ cond = (fy<0.5f) && (ty>1.0f);         oy =  0.5f; }
  else if (c==3){ cond = (fx>0.5f) && (tx<(float)W-1.0f); ox = -0.5f; }
  else if (c==4){ cond = (fy>0.5f) && (ty<(float)H-1.0f); oy = -0.5f; }

  double vbox=0.0, vcls=0.0, vcnt=0.0, vobj=0.0;
  if (sel && cond){
    const int gridx = (int)(tx - ox);      // trunc toward zero, matches astype(int32)
    const int gridy = (int)(ty - oy);
    const float gxx = tx - (float)gridx;
    const float gyy = ty - (float)gridy;
    const int gx = min(max(gridx,0), W-1);
    const int gy = min(max(gridy,0), H-1);
    const int im = (int)t0;
    const int ci = (int)t1;
    const long HW = (long)H*W;
    const float* base = p + ((long)(im*255 + a*85)*H + gy)*W + gx;

    const float o0=base[0], o1=base[HW], o2=base[2*HW], o3=base[3*HW], o4=base[4*HW];
    const float px = sigm(o0)*2.f - 0.5f;
    const float py = sigm(o1)*2.f - 0.5f;
    const float s2 = sigm(o2)*2.f; const float pw = s2*s2*aw;
    const float s3 = sigm(o3)*2.f; const float ph = s3*s3*ah;

    // GIoU exactly as the reference computes it (corners first)
    const float ax0=px-pw/2.f, ax1=px+pw/2.f, ay0=py-ph/2.f, ay1=py+ph/2.f;
    const float bx0=gxx-tw/2.f, bx1=gxx+tw/2.f, by0=gyy-th/2.f, by1=gyy+th/2.f;
    const float iw = fmaxf(fminf(ax1,bx1)-fmaxf(ax0,bx0), 0.f);
    const float ih = fmaxf(fminf(ay1,by1)-fmaxf(ay0,by0), 0.f);
    const float inter = iw*ih;
    const float uni = (ax1-ax0)*(ay1-ay0) + (bx1-bx0)*(by1-by0) - inter;
    const float iou = inter/uni;
    const float cwid = fmaxf(ax1,bx1)-fminf(ax0,bx0)+1e-16f;
    const float chei = fmaxf(ay1,by1)-fminf(ay0,by0);
    const float ca = cwid*chei + 1e-16f;
    const float g = iou - (ca-uni)/ca;

    vbox = (double)(1.0f - g);
    vcnt = 1.0;
    // obj_gt scatter replaced by correction: bce(x,g)-bce(x,0) = -x*g
    vobj = -(double)o4 * (double)fmaxf(g, 0.f);

    float cs = 0.f;
    #pragma unroll 4
    for (int k=0; k<NCLS; k++){
      const float x = base[(long)(5+k)*HW];
      cs += bcel(x, (k==ci) ? 1.0f : 0.0f);
    }
    vcls = (double)cs;
  }

  vbox = wred(vbox); vcls = wred(vcls); vcnt = wred(vcnt); vobj = wred(vobj);
  if ((threadIdx.x & 63) == 0){
    atomicAdd(&acc[LVL*4+0], vbox);
    atomicAdd(&acc[LVL*4+1], vcls);
    atomicAdd(&acc[LVL*4+2], vcnt);
    atomicAdd(&acc[LVL*4+3], vobj);
  }
}

// Weighted softplus over the objectness channel of all 3 levels.
__global__ __launch_bounds__(256)
void k_obj(const float* __restrict__ p0, const float* __restrict__ p1,
           const float* __restrict__ p2, double* __restrict__ acc)
{
  const int TOT = 403200;   // 307200 + 76800 + 19200
  double s = 0.0;
  for (int i = blockIdx.x*blockDim.x + threadIdx.x; i < TOT;
       i += gridDim.x*blockDim.x){
    float x; double w;
    if (i < 307200){
      const int b=i/19200, r=i%19200, a=r/6400, pos=r%6400;
      x = p0[((long)(b*255 + a*85 + 4))*6400 + pos];
      w = 4.0/307200.0;
    } else if (i < 384000){
      const int j=i-307200;
      const int b=j/4800, r=j%4800, a=r/1600, pos=r%1600;
      x = p1[((long)(b*255 + a*85 + 4))*1600 + pos];
      w = 1.0/76800.0;
    } else {
      const int j=i-384000;
      const int b=j/1200, r=j%1200, a=r/400, pos=r%400;
      x = p2[((long)(b*255 + a*85 + 4))*400 + pos];
      w = 0.4/19200.0;
    }
    const float sp = fmaxf(x,0.f) + log1pf(expf(-fabsf(x)));
    s += w * (double)sp;
  }
  s = wred(s);
  __shared__ double sh[4];
  if ((threadIdx.x & 63) == 0) sh[threadIdx.x>>6] = s;
  __syncthreads();
  if (threadIdx.x == 0){
    atomicAdd(&acc[12], sh[0]+sh[1]+sh[2]+sh[3]);
  }
}

__global__ void k_final(const double* __restrict__ acc, float* __restrict__ out)
{
  double lbox = 0.0, lcls = 0.0;
  double lobj = acc[12];
  const double bal[3] = {4.0, 1.0, 0.4};
  const double sz[3]  = {307200.0, 76800.0, 19200.0};
  for (int l=0; l<3; l++){
    const double cnt = acc[l*4+2];
    const double den = cnt > 1.0 ? cnt : 1.0;
    if (cnt > 0.0){
      lbox += acc[l*4+0] / den;
      lcls += acc[l*4+1] / (den * 80.0);
    }
    lobj += bal[l] * acc[l*4+3] / sz[l];
  }
  const double loss = (0.05*lbox + 1.0*lobj + 0.5*lcls) * 16.0;
  out[0] = (float)loss;
}

extern "C" void kernel_launch(void* const* d_in, const int* in_sizes, int n_in,
                              void* d_out, int out_size, void* d_ws, size_t ws_size,
                              hipStream_t stream)
{
  const float* p0 = (const float*)d_in[0];
  const float* p1 = (const float*)d_in[1];
  const float* p2 = (const float*)d_in[2];
  const float* tg = (const float*)d_in[3];
  double* acc = (double*)d_ws;

  hipMemsetAsync(d_ws, 0, 16*sizeof(double), stream);
  k_entries<0,80,80><<<30,256,0,stream>>>(p0, tg, acc);
  k_entries<1,40,40><<<30,256,0,stream>>>(p1, tg, acc);
  k_entries<2,20,20><<<30,256,0,stream>>>(p2, tg, acc);
  k_obj<<<420,256,0,stream>>>(p0, p1, p2, acc);
  k_final<<<1,1,0,stream>>>(acc, (float*)d_out);
}